// Round 5
// baseline (239.201 us; speedup 1.0000x reference)
//
#include <hip/hip_runtime.h>

typedef __bf16 bf16x8 __attribute__((ext_vector_type(8)));
typedef float  f32x4  __attribute__((ext_vector_type(4)));
typedef float  f32x16 __attribute__((ext_vector_type(16)));
typedef unsigned int   u32x4 __attribute__((ext_vector_type(4)));
typedef unsigned short u16x4 __attribute__((ext_vector_type(4)));

#define NB   4
#define NC   256
#define NN   4096
#define NO   768
#define NPG  131072
#define KVB  32

#define AS1 __attribute__((address_space(1)))
#define AS3 __attribute__((address_space(3)))

__device__ __forceinline__ unsigned short f2b(float f){
  unsigned int u = __builtin_bit_cast(unsigned int, f);
  u += 0x7fff + ((u >> 16) & 1);           // RTNE
  return (unsigned short)(u >> 16);
}
__device__ __forceinline__ float b2f(unsigned short s){
  unsigned int u = (unsigned int)s << 16;
  return __builtin_bit_cast(float, u);
}

// XOR swizzle in ushort units (16B-chunk granularity)
#define SWZ(e, r) ((e) ^ (((r) & 7) << 3))

// ---------------- K1: GroupNorm partial stats -----------------------------
__global__ void gn_stats(const float* __restrict__ x, float* __restrict__ part){
  const f32x4* p = (const f32x4*)x + (size_t)blockIdx.x * 4096;
  float s = 0.f, ss = 0.f;
  for (int i = threadIdx.x; i < 4096; i += 256){
    f32x4 v = p[i];
    s  += v[0] + v[1] + v[2] + v[3];
    ss += v[0]*v[0] + v[1]*v[1] + v[2]*v[2] + v[3]*v[3];
  }
  #pragma unroll
  for (int o = 32; o; o >>= 1){ s += __shfl_down(s, o); ss += __shfl_down(ss, o); }
  __shared__ float red[8];
  int wid = threadIdx.x >> 6;
  if ((threadIdx.x & 63) == 0){ red[wid] = s; red[wid + 4] = ss; }
  __syncthreads();
  if (threadIdx.x == 0){
    part[blockIdx.x*2]     = red[0] + red[1] + red[2] + red[3];
    part[blockIdx.x*2 + 1] = red[4] + red[5] + red[6] + red[7];
  }
}

// ---------------- K2: apply GN -> hn bf16 [b][c][n] -----------------------
__global__ void gn_apply(const float* __restrict__ x, const float* __restrict__ part,
                         const float* __restrict__ nw, const float* __restrict__ nb,
                         unsigned short* __restrict__ hn){
  size_t i4 = (size_t)blockIdx.x * 256 + threadIdx.x;
  int bg = (int)(i4 >> 15);
  int c  = (int)((i4 >> 10) & 255);
  float s = 0.f, ss = 0.f;
  #pragma unroll
  for (int p2 = 0; p2 < 8; ++p2){
    s  += part[(bg*8 + p2)*2];
    ss += part[(bg*8 + p2)*2 + 1];
  }
  float mean = s * (1.f / NPG);
  float var  = ss * (1.f / NPG) - mean * mean;
  float rstd = rsqrtf(var + 1e-5f);
  float w  = nw[c] * rstd;
  float bb = nb[c] - mean * w;
  f32x4 v = ((const f32x4*)x)[i4];
  u16x4 o4;
  o4[0] = f2b(v[0]*w + bb); o4[1] = f2b(v[1]*w + bb);
  o4[2] = f2b(v[2]*w + bb); o4[3] = f2b(v[3]*w + bb);
  ((u16x4*)hn)[i4] = o4;
}

// ---------------- K3: QKV GEMM -> qsep[b][n][c] (x1/16), ksep, vsep -------
__global__ __launch_bounds__(256) void qkv_gemm(
    const unsigned short* __restrict__ hn, const float* __restrict__ W,
    const float* __restrict__ bias, unsigned short* __restrict__ qsep,
    unsigned short* __restrict__ ksep, unsigned short* __restrict__ vsep){
  __shared__ __align__(16) unsigned short a_lds[128*32];
  __shared__ __align__(16) unsigned short b_lds[128*32];
  const int n0 = blockIdx.x * 128, o0 = blockIdx.y * 128, b = blockIdx.z;
  const unsigned short* hb = hn + (size_t)b * NC * NN;
  const int t = threadIdx.x, lane = t & 63, wid = t >> 6;
  const int wm = wid >> 1, wn = wid & 1;
  const int l15 = lane & 15, lk = (lane >> 4) * 8;
  f32x4 acc[4][4] = {};
  for (int k0 = 0; k0 < NC; k0 += 32){
    __syncthreads();
    for (int ch = t; ch < 512; ch += 256){          // A: W fp32 -> bf16
      int row = ch >> 2, kc = (ch & 3) * 8;
      const float* src = W + (size_t)(o0 + row) * NC + k0 + kc;
      unsigned short tmp[8];
      #pragma unroll
      for (int e = 0; e < 8; ++e) tmp[e] = f2b(src[e]);
      *(u32x4*)&a_lds[SWZ(row*32 + kc, row)] = *(u32x4*)tmp;
    }
    for (int ch = t; ch < 512; ch += 256){          // B: hn -> [n][k]
      int kk = ch >> 4, j8 = (ch & 15) * 8;
      const unsigned short* src = hb + (size_t)(k0 + kk) * NN + n0 + j8;
      unsigned short tmp[8];
      *(u32x4*)tmp = *(const u32x4*)src;
      #pragma unroll
      for (int e = 0; e < 8; ++e) b_lds[SWZ((j8+e)*32 + kk, j8+e)] = tmp[e];
    }
    __syncthreads();
    bf16x8 af[4], bfr[4];
    #pragma unroll
    for (int mf = 0; mf < 4; ++mf){
      int r = wm*64 + mf*16 + l15;
      af[mf] = __builtin_bit_cast(bf16x8, *(u32x4*)&a_lds[SWZ(r*32 + lk, r)]);
    }
    #pragma unroll
    for (int nf = 0; nf < 4; ++nf){
      int r = wn*64 + nf*16 + l15;
      bfr[nf] = __builtin_bit_cast(bf16x8, *(u32x4*)&b_lds[SWZ(r*32 + lk, r)]);
    }
    #pragma unroll
    for (int mf = 0; mf < 4; ++mf)
      #pragma unroll
      for (int nf = 0; nf < 4; ++nf)
        acc[mf][nf] = __builtin_amdgcn_mfma_f32_16x16x32_bf16(af[mf], bfr[nf], acc[mf][nf], 0, 0, 0);
  }
  size_t nb_ = (size_t)b * NN * NC;
  unsigned short* vs = vsep + (size_t)b * NC * NN;
  #pragma unroll
  for (int mf = 0; mf < 4; ++mf){
    int ob = o0 + wm*64 + mf*16 + ((lane >> 4) << 2);
    float b0 = bias[ob], b1 = bias[ob+1], b2 = bias[ob+2], b3 = bias[ob+3];
    #pragma unroll
    for (int nf = 0; nf < 4; ++nf){
      int n = n0 + wn*64 + nf*16 + l15;
      f32x4 a = acc[mf][nf];
      u16x4 stv;
      if (ob < 256){          // Q: fold softmax scale 1/16
        stv[0] = f2b((a[0] + b0)*0.0625f); stv[1] = f2b((a[1] + b1)*0.0625f);
        stv[2] = f2b((a[2] + b2)*0.0625f); stv[3] = f2b((a[3] + b3)*0.0625f);
        *(u16x4*)(qsep + nb_ + (size_t)n * NC + ob) = stv;
      } else if (ob < 512){
        stv[0] = f2b(a[0] + b0); stv[1] = f2b(a[1] + b1);
        stv[2] = f2b(a[2] + b2); stv[3] = f2b(a[3] + b3);
        *(u16x4*)(ksep + nb_ + (size_t)n * NC + (ob - 256)) = stv;
      } else {
        stv[0] = f2b(a[0] + b0); stv[1] = f2b(a[1] + b1);
        stv[2] = f2b(a[2] + b2); stv[3] = f2b(a[3] + b3);
        vs[(size_t)(ob - 512 + 0) * NN + n] = stv[0];
        vs[(size_t)(ob - 512 + 1) * NN + n] = stv[1];
        vs[(size_t)(ob - 512 + 2) * NN + n] = stv[2];
        vs[(size_t)(ob - 512 + 3) * NN + n] = stv[3];
      }
    }
  }
}

// ---------------- K4: flash attention, 32x32 MFMA, in-register P ----------
// V LDS permutation: logical chunk l (= c*4 + k) stored at p = l ^ (c&7)
// (bijective across rows; read addr = e ^ ((c&7)<<3); staging source uses
//  inverse l0=p0^p2^p4, l1=p1^p3, l2=p2^p4).
__global__ __launch_bounds__(256, 2) void attn(
    const unsigned short* __restrict__ qsep,
    const unsigned short* __restrict__ ksep,
    const unsigned short* __restrict__ vsep,
    unsigned short* __restrict__ opart, float* __restrict__ ml){
  __shared__ __align__(16) unsigned short k_lds[2][KVB*256];
  __shared__ __align__(16) unsigned short v_lds[2][256*KVB];
  const int swzb = (blockIdx.x & 7) * 64 + (blockIdx.x >> 3);
  const int part = swzb >> 7;
  const int b    = (swzb >> 5) & 3;
  const int i0   = (swzb & 31) * 128;
  const int jbase = part * 1024;
  const unsigned short* qb_ = qsep + (size_t)b * NN * NC;
  const unsigned short* kb_ = ksep + (size_t)b * NN * NC;
  const unsigned short* vb_ = vsep + (size_t)b * NC * NN;
  const int t = threadIdx.x, lane = t & 63, wid = t >> 6;
  const int l31 = lane & 31, hi = lane >> 5;

  bf16x8 qf[16];
  {
    const unsigned short* qrow = qb_ + (size_t)(i0 + wid*32 + l31) * NC + hi*8;
    #pragma unroll
    for (int ks = 0; ks < 16; ++ks)
      qf[ks] = __builtin_bit_cast(bf16x8, *(const u32x4*)&qrow[ks*16]);
  }

  int koff[4], voff[4];
  #pragma unroll
  for (int q = 0; q < 4; ++q){
    int jr = (wid*4 + q)*2 + (lane >> 5);
    int cc = (lane & 31) ^ (jr & 7);
    koff[q] = jr*256 + cc*8;
    int p = (wid*4 + q)*64 + lane;               // physical V chunk
    int l = (p & ~7) | ((((p>>2)^(p>>4))&1)<<2)
                     | ((((p>>1)^(p>>3))&1)<<1)
                     | ((p ^ (p>>2) ^ (p>>4)) & 1);
    voff[q] = (l >> 2)*NN + (l & 3)*8;           // channel row + 16B chunk
  }

  auto stage = [&](int buf, int j0) __attribute__((always_inline)) {
    #pragma unroll
    for (int q = 0; q < 4; ++q)
      __builtin_amdgcn_global_load_lds(
          (AS1 const unsigned int*)(kb_ + j0*256 + koff[q]),
          (AS3 unsigned int*)&k_lds[buf][(wid*4 + q)*512], 16, 0, 0);
    #pragma unroll
    for (int q = 0; q < 4; ++q)
      __builtin_amdgcn_global_load_lds(
          (AS1 const unsigned int*)(vb_ + voff[q] + j0),
          (AS3 unsigned int*)&v_lds[buf][(wid*4 + q)*512], 16, 0, 0);
  };

  f32x16 oa[8] = {};
  float m_run = -3.0e38f, l_run = 0.f;

  stage(0, jbase);
  for (int jt = 0; jt < 32; ++jt){
    const int cur = jt & 1;
    if (jt < 31){
      stage(cur ^ 1, jbase + (jt + 1) * KVB);
      asm volatile("s_waitcnt vmcnt(8)" ::: "memory");
    } else {
      asm volatile("s_waitcnt vmcnt(0)" ::: "memory");
    }
    __builtin_amdgcn_sched_barrier(0);
    __builtin_amdgcn_s_barrier();
    __builtin_amdgcn_sched_barrier(0);

    const unsigned short* kl = k_lds[cur];
    const unsigned short* vl = v_lds[cur];
    // S^T = K @ Q^T, two independent 8-deep accumulation chains
    f32x16 sa = {}, sb = {};
    __builtin_amdgcn_s_setprio(1);
    #pragma unroll
    for (int ks = 0; ks < 8; ++ks){
      int ea = l31*256 + (2*ks)*16 + hi*8;
      bf16x8 ka = __builtin_bit_cast(bf16x8, *(const u32x4*)&kl[SWZ(ea, l31)]);
      sa = __builtin_amdgcn_mfma_f32_32x32x16_bf16(ka, qf[2*ks], sa, 0, 0, 0);
      int eb = l31*256 + (2*ks+1)*16 + hi*8;
      bf16x8 kb2 = __builtin_bit_cast(bf16x8, *(const u32x4*)&kl[SWZ(eb, l31)]);
      sb = __builtin_amdgcn_mfma_f32_32x32x16_bf16(kb2, qf[2*ks+1], sb, 0, 0, 0);
    }
    __builtin_amdgcn_s_setprio(0);
    f32x16 st = sa + sb;
    // tree max over 16 regs, then cross-half
    float m8[8];
    #pragma unroll
    for (int i = 0; i < 8; ++i) m8[i] = fmaxf(st[i], st[i+8]);
    #pragma unroll
    for (int o = 4; o; o >>= 1)
      #pragma unroll
      for (int i = 0; i < 4; ++i) if (i < o) m8[i] = fmaxf(m8[i], m8[i+o]);
    float mx = fmaxf(m8[0], __shfl_xor(m8[0], 32));
    if (!__all(mx <= m_run + 8.f)){
      float mnew  = fmaxf(m_run, mx);
      float alpha = __expf(m_run - mnew);
      m_run = mnew; l_run *= alpha;
      #pragma unroll
      for (int tt = 0; tt < 8; ++tt) oa[tt] *= alpha;
    }
    float p[16];
    #pragma unroll
    for (int r = 0; r < 16; ++r) p[r] = __expf(st[r] - m_run);
    float s8[8];
    #pragma unroll
    for (int i = 0; i < 8; ++i) s8[i] = p[i] + p[i+8];
    #pragma unroll
    for (int o = 4; o; o >>= 1)
      #pragma unroll
      for (int i = 0; i < 4; ++i) if (i < o) s8[i] += s8[i+o];
    l_run += s8[0] + __shfl_xor(s8[0], 32);
    // pack P^T into B-frags: regs r -> j=(r&3)+8*(r>>2)+4*hi
    unsigned int w[8];
    #pragma unroll
    for (int r = 0; r < 8; ++r){
      unsigned int pk;
      asm("v_cvt_pk_bf16_f32 %0, %1, %2" : "=v"(pk) : "v"(p[2*r]), "v"(p[2*r+1]));
      w[r] = pk;
    }
    asm("v_permlane32_swap_b32 %0, %1" : "+v"(w[0]), "+v"(w[2]));
    asm("v_permlane32_swap_b32 %0, %1" : "+v"(w[1]), "+v"(w[3]));
    asm("v_permlane32_swap_b32 %0, %1" : "+v"(w[4]), "+v"(w[6]));
    asm("v_permlane32_swap_b32 %0, %1" : "+v"(w[5]), "+v"(w[7]));
    u32x4 pb0v = {w[0], w[1], w[2], w[3]};
    u32x4 pb1v = {w[4], w[5], w[6], w[7]};
    bf16x8 pb0 = __builtin_bit_cast(bf16x8, pb0v);   // k = j 0..15
    bf16x8 pb1 = __builtin_bit_cast(bf16x8, pb1v);   // k = j 16..31
    // O^T += V^T @ P^T
    __builtin_amdgcn_s_setprio(1);
    #pragma unroll
    for (int ct = 0; ct < 8; ++ct){
      int c = ct*32 + l31;
      int sw = (c & 7) << 3;
      bf16x8 va0 = __builtin_bit_cast(bf16x8, *(const u32x4*)&vl[(c*KVB + hi*8) ^ sw]);
      oa[ct] = __builtin_amdgcn_mfma_f32_32x32x16_bf16(va0, pb0, oa[ct], 0, 0, 0);
      bf16x8 va1 = __builtin_bit_cast(bf16x8, *(const u32x4*)&vl[(c*KVB + hi*8 + 16) ^ sw]);
      oa[ct] = __builtin_amdgcn_mfma_f32_32x32x16_bf16(va1, pb1, oa[ct], 0, 0, 0);
    }
    __builtin_amdgcn_s_setprio(0);
    __builtin_amdgcn_sched_barrier(0);
    __builtin_amdgcn_s_barrier();
    __builtin_amdgcn_sched_barrier(0);
  }

  size_t orow = ((size_t)(part*4 + b) * NN + i0 + wid*32 + l31) * NC;
  #pragma unroll
  for (int ct = 0; ct < 8; ++ct){
    #pragma unroll
    for (int rq = 0; rq < 4; ++rq){
      unsigned int lo, hi2;
      asm("v_cvt_pk_bf16_f32 %0, %1, %2" : "=v"(lo)  : "v"(oa[ct][4*rq+0]), "v"(oa[ct][4*rq+1]));
      asm("v_cvt_pk_bf16_f32 %0, %1, %2" : "=v"(hi2) : "v"(oa[ct][4*rq+2]), "v"(oa[ct][4*rq+3]));
      int c = ct*32 + rq*8 + 4*hi;
      uint2 pkv; pkv.x = lo; pkv.y = hi2;
      *(uint2*)(opart + orow + c) = pkv;
    }
  }
  if (lane < 32){
    float2 mlv; mlv.x = m_run; mlv.y = l_run;
    ((float2*)ml)[(size_t)(part*4 + b) * NN + i0 + wid*32 + lane] = mlv;
  }
}

// ---------------- K4b: merge the four KV-quarters -------------------------
__global__ __launch_bounds__(256) void attn_merge(
    const unsigned short* __restrict__ opart, const float* __restrict__ ml,
    unsigned short* __restrict__ ot){
  const int t = threadIdx.x;
  const int row = blockIdx.x * 8 + (t >> 5);
  const int c0 = (t & 31) * 8;
  const float2* mlp = (const float2*)ml;
  float2 m0 = mlp[row], m1 = mlp[16384 + row], m2 = mlp[32768 + row], m3 = mlp[49152 + row];
  float M = fmaxf(fmaxf(m0.x, m1.x), fmaxf(m2.x, m3.x));
  float w0 = __expf(m0.x - M), w1 = __expf(m1.x - M);
  float w2 = __expf(m2.x - M), w3 = __expf(m3.x - M);
  float inv = 1.f / (w0*m0.y + w1*m1.y + w2*m2.y + w3*m3.y);
  w0 *= inv; w1 *= inv; w2 *= inv; w3 *= inv;
  const size_t base = (size_t)row * NC + c0;
  const size_t ps = (size_t)16384 * NC;
  u16x4 a0 = *(const u16x4*)(opart + base),        a1 = *(const u16x4*)(opart + base + 4);
  u16x4 b0 = *(const u16x4*)(opart + base + ps),   b1 = *(const u16x4*)(opart + base + ps + 4);
  u16x4 c0v = *(const u16x4*)(opart + base + 2*ps), c1 = *(const u16x4*)(opart + base + 2*ps + 4);
  u16x4 d0 = *(const u16x4*)(opart + base + 3*ps), d1 = *(const u16x4*)(opart + base + 3*ps + 4);
  u16x4 o0, o1;
  #pragma unroll
  for (int k = 0; k < 4; ++k){
    o0[k] = f2b(w0*b2f(a0[k]) + w1*b2f(b0[k]) + w2*b2f(c0v[k]) + w3*b2f(d0[k]));
    o1[k] = f2b(w0*b2f(a1[k]) + w1*b2f(b1[k]) + w2*b2f(c1[k]) + w3*b2f(d1[k]));
  }
  unsigned short* dst = ot + base;
  *(u16x4*)dst = o0; *(u16x4*)(dst + 4) = o1;
}

// ---------------- K5: out-proj + bias + residual --------------------------
__global__ __launch_bounds__(256) void out_proj(
    const unsigned short* __restrict__ ot, const float* __restrict__ W,
    const float* __restrict__ bias, const float* __restrict__ x,
    float* __restrict__ out){
  __shared__ __align__(16) unsigned short a_lds[128*32];
  __shared__ __align__(16) unsigned short b_lds[128*32];
  const int n0 = blockIdx.x * 128, oc0 = blockIdx.y * 128, b = blockIdx.z;
  const unsigned short* ob_ = ot + (size_t)b * NN * NC;
  const int t = threadIdx.x, lane = t & 63, wid = t >> 6;
  const int wm = wid >> 1, wn = wid & 1;
  const int l15 = lane & 15, lk = (lane >> 4) * 8;
  f32x4 acc[4][4] = {};
  for (int k0 = 0; k0 < NC; k0 += 32){
    __syncthreads();
    for (int ch = t; ch < 512; ch += 256){
      int row = ch >> 2, kc = (ch & 3) * 8;
      *(u32x4*)&a_lds[SWZ(row*32 + kc, row)] =
          *(const u32x4*)&ob_[(size_t)(n0 + row) * NC + k0 + kc];
    }
    for (int ch = t; ch < 512; ch += 256){
      int row = ch >> 2, kc = (ch & 3) * 8;
      const float* src = W + (size_t)(oc0 + row) * NC + k0 + kc;
      unsigned short tmp[8];
      #pragma unroll
      for (int e = 0; e < 8; ++e) tmp[e] = f2b(src[e]);
      *(u32x4*)&b_lds[SWZ(row*32 + kc, row)] = *(u32x4*)tmp;
    }
    __syncthreads();
    bf16x8 af[4], bfr[4];
    #pragma unroll
    for (int mf = 0; mf < 4; ++mf){
      int r = wm*64 + mf*16 + l15;
      af[mf] = __builtin_bit_cast(bf16x8, *(u32x4*)&a_lds[SWZ(r*32 + lk, r)]);
    }
    #pragma unroll
    for (int nf = 0; nf < 4; ++nf){
      int r = wn*64 + nf*16 + l15;
      bfr[nf] = __builtin_bit_cast(bf16x8, *(u32x4*)&b_lds[SWZ(r*32 + lk, r)]);
    }
    #pragma unroll
    for (int mf = 0; mf < 4; ++mf)
      #pragma unroll
      for (int nf = 0; nf < 4; ++nf)
        acc[mf][nf] = __builtin_amdgcn_mfma_f32_16x16x32_bf16(af[mf], bfr[nf], acc[mf][nf], 0, 0, 0);
  }
  #pragma unroll
  for (int nf = 0; nf < 4; ++nf){
    int oc = oc0 + wn*64 + nf*16 + l15;
    float bb = bias[oc];
    #pragma unroll
    for (int mf = 0; mf < 4; ++mf){
      int n = n0 + wm*64 + mf*16 + ((lane >> 4) << 2);
      size_t off = ((size_t)b * NC + oc) * NN + n;
      f32x4 xv = *(const f32x4*)&x[off];
      f32x4 r = acc[mf][nf] + xv + bb;
      *(f32x4*)&out[off] = r;
    }
  }
}

extern "C" void kernel_launch(void* const* d_in, const int* in_sizes, int n_in,
                              void* d_out, int out_size, void* d_ws, size_t ws_size,
                              hipStream_t stream){
  const float* x    = (const float*)d_in[0];
  const float* nw   = (const float*)d_in[1];
  const float* nbv  = (const float*)d_in[2];
  const float* qkvw = (const float*)d_in[3];
  const float* qkvb = (const float*)d_in[4];
  const float* outw = (const float*)d_in[5];
  const float* outb = (const float*)d_in[6];
  float* out = (float*)d_out;
  char* ws = (char*)d_ws;
  float*          part  = (float*)ws;                              // 4 KB
  unsigned short* opart = (unsigned short*)(ws + 4096);            // 32 MB
  unsigned short* hn    = (unsigned short*)(ws + 4096);            // 8 MB (dead before attn)
  unsigned short* qsep  = (unsigned short*)(ws + 4096 + 33554432); // 8 MB
  unsigned short* ksep  = qsep + (size_t)NB*NN*NC;                 // 8 MB
  unsigned short* vsep  = ksep + (size_t)NB*NN*NC;                 // 8 MB
  float*          ml    = (float*)(vsep + (size_t)NB*NN*NC);       // 512 KB
  unsigned short* ot    = qsep;   // qsep dead after attn; reuse for merged O

  gn_stats<<<256, 256, 0, stream>>>(x, part);
  gn_apply<<<4096, 256, 0, stream>>>(x, part, nw, nbv, hn);
  qkv_gemm<<<dim3(32, 6, 4), 256, 0, stream>>>(hn, qkvw, qkvb, qsep, ksep, vsep);
  attn<<<dim3(512), 256, 0, stream>>>(qsep, ksep, vsep, opart, ml);
  attn_merge<<<dim3(2048), 256, 0, stream>>>(opart, ml, ot);
  out_proj<<<dim3(32, 2, 4), 256, 0, stream>>>(ot, outw, outb, x, out);
}

// Round 8
// 181.879 us; speedup vs baseline: 1.3152x; 1.3152x over previous
//
#include <hip/hip_runtime.h>

typedef __bf16 bf16x8 __attribute__((ext_vector_type(8)));
typedef float  f32x4  __attribute__((ext_vector_type(4)));
typedef float  f32x16 __attribute__((ext_vector_type(16)));
typedef unsigned int   u32x4 __attribute__((ext_vector_type(4)));
typedef unsigned short u16x4 __attribute__((ext_vector_type(4)));

#define NB   4
#define NC   256
#define NN   4096
#define NO   768
#define NPG  131072
#define KVB  32

#define AS1 __attribute__((address_space(1)))
#define AS3 __attribute__((address_space(3)))

__device__ __forceinline__ unsigned short f2b(float f){
  unsigned int u = __builtin_bit_cast(unsigned int, f);
  u += 0x7fff + ((u >> 16) & 1);           // RTNE
  return (unsigned short)(u >> 16);
}
__device__ __forceinline__ float b2f(unsigned short s){
  unsigned int u = (unsigned int)s << 16;
  return __builtin_bit_cast(float, u);
}

// XOR swizzle in ushort units (16B-chunk granularity)
#define SWZ(e, r) ((e) ^ (((r) & 7) << 3))

// ---------------- K1: GroupNorm partial stats -----------------------------
__global__ void gn_stats(const float* __restrict__ x, float* __restrict__ part){
  const f32x4* p = (const f32x4*)x + (size_t)blockIdx.x * 4096;
  float s = 0.f, ss = 0.f;
  for (int i = threadIdx.x; i < 4096; i += 256){
    f32x4 v = p[i];
    s  += v[0] + v[1] + v[2] + v[3];
    ss += v[0]*v[0] + v[1]*v[1] + v[2]*v[2] + v[3]*v[3];
  }
  #pragma unroll
  for (int o = 32; o; o >>= 1){ s += __shfl_down(s, o); ss += __shfl_down(ss, o); }
  __shared__ float red[8];
  int wid = threadIdx.x >> 6;
  if ((threadIdx.x & 63) == 0){ red[wid] = s; red[wid + 4] = ss; }
  __syncthreads();
  if (threadIdx.x == 0){
    part[blockIdx.x*2]     = red[0] + red[1] + red[2] + red[3];
    part[blockIdx.x*2 + 1] = red[4] + red[5] + red[6] + red[7];
  }
}

// ---------------- K2: apply GN -> hn bf16 [b][c][n] -----------------------
__global__ void gn_apply(const float* __restrict__ x, const float* __restrict__ part,
                         const float* __restrict__ nw, const float* __restrict__ nb,
                         unsigned short* __restrict__ hn){
  size_t i4 = (size_t)blockIdx.x * 256 + threadIdx.x;
  int bg = (int)(i4 >> 15);
  int c  = (int)((i4 >> 10) & 255);
  float s = 0.f, ss = 0.f;
  #pragma unroll
  for (int p2 = 0; p2 < 8; ++p2){
    s  += part[(bg*8 + p2)*2];
    ss += part[(bg*8 + p2)*2 + 1];
  }
  float mean = s * (1.f / NPG);
  float var  = ss * (1.f / NPG) - mean * mean;
  float rstd = rsqrtf(var + 1e-5f);
  float w  = nw[c] * rstd;
  float bb = nb[c] - mean * w;
  f32x4 v = ((const f32x4*)x)[i4];
  u16x4 o4;
  o4[0] = f2b(v[0]*w + bb); o4[1] = f2b(v[1]*w + bb);
  o4[2] = f2b(v[2]*w + bb); o4[3] = f2b(v[3]*w + bb);
  ((u16x4*)hn)[i4] = o4;
}

// ---------------- K3: QKV GEMM -> qsep[b][n][c], ksep[b][n][c], vsep[b][c][n]
__global__ __launch_bounds__(256) void qkv_gemm(
    const unsigned short* __restrict__ hn, const float* __restrict__ W,
    const float* __restrict__ bias, unsigned short* __restrict__ qsep,
    unsigned short* __restrict__ ksep, unsigned short* __restrict__ vsep){
  __shared__ __align__(16) unsigned short a_lds[128*32];
  __shared__ __align__(16) unsigned short b_lds[128*32];
  const int n0 = blockIdx.x * 128, o0 = blockIdx.y * 128, b = blockIdx.z;
  const unsigned short* hb = hn + (size_t)b * NC * NN;
  const int t = threadIdx.x, lane = t & 63, wid = t >> 6;
  const int wm = wid >> 1, wn = wid & 1;
  const int l15 = lane & 15, lk = (lane >> 4) * 8;
  f32x4 acc[4][4] = {};
  for (int k0 = 0; k0 < NC; k0 += 32){
    __syncthreads();
    for (int ch = t; ch < 512; ch += 256){          // A: W fp32 -> bf16
      int row = ch >> 2, kc = (ch & 3) * 8;
      const float* src = W + (size_t)(o0 + row) * NC + k0 + kc;
      unsigned short tmp[8];
      #pragma unroll
      for (int e = 0; e < 8; ++e) tmp[e] = f2b(src[e]);
      *(u32x4*)&a_lds[SWZ(row*32 + kc, row)] = *(u32x4*)tmp;
    }
    for (int ch = t; ch < 512; ch += 256){          // B: hn -> [n][k]
      int kk = ch >> 4, j8 = (ch & 15) * 8;
      const unsigned short* src = hb + (size_t)(k0 + kk) * NN + n0 + j8;
      unsigned short tmp[8];
      *(u32x4*)tmp = *(const u32x4*)src;
      #pragma unroll
      for (int e = 0; e < 8; ++e) b_lds[SWZ((j8+e)*32 + kk, j8+e)] = tmp[e];
    }
    __syncthreads();
    bf16x8 af[4], bfr[4];
    #pragma unroll
    for (int mf = 0; mf < 4; ++mf){
      int r = wm*64 + mf*16 + l15;
      af[mf] = __builtin_bit_cast(bf16x8, *(u32x4*)&a_lds[SWZ(r*32 + lk, r)]);
    }
    #pragma unroll
    for (int nf = 0; nf < 4; ++nf){
      int r = wn*64 + nf*16 + l15;
      bfr[nf] = __builtin_bit_cast(bf16x8, *(u32x4*)&b_lds[SWZ(r*32 + lk, r)]);
    }
    #pragma unroll
    for (int mf = 0; mf < 4; ++mf)
      #pragma unroll
      for (int nf = 0; nf < 4; ++nf)
        acc[mf][nf] = __builtin_amdgcn_mfma_f32_16x16x32_bf16(af[mf], bfr[nf], acc[mf][nf], 0, 0, 0);
  }
  size_t nb_ = (size_t)b * NN * NC;
  unsigned short* vs = vsep + (size_t)b * NC * NN;
  #pragma unroll
  for (int mf = 0; mf < 4; ++mf){
    int ob = o0 + wm*64 + mf*16 + ((lane >> 4) << 2);
    float b0 = bias[ob], b1 = bias[ob+1], b2 = bias[ob+2], b3 = bias[ob+3];
    #pragma unroll
    for (int nf = 0; nf < 4; ++nf){
      int n = n0 + wn*64 + nf*16 + l15;
      f32x4 a = acc[mf][nf];
      u16x4 stv;
      stv[0] = f2b(a[0] + b0); stv[1] = f2b(a[1] + b1);
      stv[2] = f2b(a[2] + b2); stv[3] = f2b(a[3] + b3);
      if (ob < 256){
        *(u16x4*)(qsep + nb_ + (size_t)n * NC + ob) = stv;
      } else if (ob < 512){
        *(u16x4*)(ksep + nb_ + (size_t)n * NC + (ob - 256)) = stv;
      } else {
        vs[(size_t)(ob - 512 + 0) * NN + n] = stv[0];
        vs[(size_t)(ob - 512 + 1) * NN + n] = stv[1];
        vs[(size_t)(ob - 512 + 2) * NN + n] = stv[2];
        vs[(size_t)(ob - 512 + 3) * NN + n] = stv[3];
      }
    }
  }
}

// ---------------- K4: flash attention, 32x32 MFMA, in-register P ----------
// KV-split-4: grid 512 = 4 parts x 4 b x 32 q-blocks(128 q). 4 waves x 32 q.
// S^T = mfma(K, Q); softmax in-register (lane pair l,l^32 shares q);
// P^T B-frags built via cvt_pk + permlane32_swap; O^T = mfma(V^T, P^T).
// RE-ANCHOR (R7): exact byte-for-byte copy of the R3 submission (attn 117us,
// passed all replays). R4-R6 variants (V 8-deep swizzle / chain-split /
// setprio / barrier rework) either regressed or mis-executed; reintroduce
// one variable at a time from THIS base.
__global__ __launch_bounds__(256, 2) void attn(
    const unsigned short* __restrict__ qsep,
    const unsigned short* __restrict__ ksep,
    const unsigned short* __restrict__ vsep,
    unsigned short* __restrict__ opart, float* __restrict__ ml){
  __shared__ __align__(16) unsigned short k_lds[2][KVB*256];  // [j][c] swz8 by j
  __shared__ __align__(16) unsigned short v_lds[2][256*KVB];  // [c][j] swz4 by c
  const int swzb = (blockIdx.x & 7) * 64 + (blockIdx.x >> 3);
  const int part = swzb >> 7;
  const int b    = (swzb >> 5) & 3;
  const int i0   = (swzb & 31) * 128;
  const int jbase = part * 1024;
  const unsigned short* qb_ = qsep + (size_t)b * NN * NC;
  const unsigned short* kb_ = ksep + (size_t)b * NN * NC;
  const unsigned short* vb_ = vsep + (size_t)b * NC * NN;
  const int t = threadIdx.x, lane = t & 63, wid = t >> 6;
  const int l31 = lane & 31, hi = lane >> 5;

  // Q: 32 rows per wave, 16 k-slices (B-frag layout: n=l31, k=hi*8+e)
  bf16x8 qf[16];
  {
    const unsigned short* qrow = qb_ + (size_t)(i0 + wid*32 + l31) * NC + hi*8;
    #pragma unroll
    for (int ks = 0; ks < 16; ++ks)
      qf[ks] = __builtin_bit_cast(bf16x8, *(const u32x4*)&qrow[ks*16]);
  }

  // staging source offsets (inverse chunk swizzle pre-applied to global addr)
  int koff[4], voff[4];
  #pragma unroll
  for (int q = 0; q < 4; ++q){
    int jr = (wid*4 + q)*2 + (lane >> 5);
    int cc = (lane & 31) ^ (jr & 7);
    koff[q] = jr*256 + cc*8;
    int c  = (wid*4 + q)*16 + (lane >> 2);
    int jj = (lane & 3) ^ ((lane >> 2) & 3);
    voff[q] = c*4096 + jj*8;
  }

  auto stage = [&](int buf, int j0) __attribute__((always_inline)) {
    #pragma unroll
    for (int q = 0; q < 4; ++q)
      __builtin_amdgcn_global_load_lds(
          (AS1 const unsigned int*)(kb_ + j0*256 + koff[q]),
          (AS3 unsigned int*)&k_lds[buf][(wid*4 + q)*512], 16, 0, 0);
    #pragma unroll
    for (int q = 0; q < 4; ++q)
      __builtin_amdgcn_global_load_lds(
          (AS1 const unsigned int*)(vb_ + voff[q] + j0),
          (AS3 unsigned int*)&v_lds[buf][(wid*4 + q)*512], 16, 0, 0);
  };

  f32x16 oa[8] = {};
  float m_run = -3.0e38f, l_run = 0.f;

  stage(0, jbase);
  for (int jt = 0; jt < 32; ++jt){
    const int cur = jt & 1;
    if (jt < 31){
      stage(cur ^ 1, jbase + (jt + 1) * KVB);
      asm volatile("s_waitcnt vmcnt(8)" ::: "memory");
    } else {
      asm volatile("s_waitcnt vmcnt(0)" ::: "memory");
    }
    __builtin_amdgcn_sched_barrier(0);
    __builtin_amdgcn_s_barrier();
    __builtin_amdgcn_sched_barrier(0);

    const unsigned short* kl = k_lds[cur];
    const unsigned short* vl = v_lds[cur];
    // S^T = K @ Q^T  (m=j 32, n=q 32, k=c 256)
    f32x16 st = {};
    #pragma unroll
    for (int ks = 0; ks < 16; ++ks){
      int e = l31*256 + ks*16 + hi*8;
      bf16x8 ka = __builtin_bit_cast(bf16x8, *(const u32x4*)&kl[SWZ(e, l31)]);
      st = __builtin_amdgcn_mfma_f32_32x32x16_bf16(ka, qf[ks], st, 0, 0, 0);
    }
    // in-register online softmax; lane holds 16 of 32 j's for q = l31
    float mx = st[0];
    #pragma unroll
    for (int r = 1; r < 16; ++r) mx = fmaxf(mx, st[r]);
    mx *= 0.0625f;
    mx = fmaxf(mx, __shfl_xor(mx, 32));
    if (!__all(mx <= m_run + 8.f)){
      float mnew  = fmaxf(m_run, mx);
      float alpha = __expf(m_run - mnew);
      m_run = mnew; l_run *= alpha;
      #pragma unroll
      for (int tt = 0; tt < 8; ++tt) oa[tt] *= alpha;
    }
    float p[16], lsum = 0.f;
    #pragma unroll
    for (int r = 0; r < 16; ++r){ p[r] = __expf(st[r]*0.0625f - m_run); lsum += p[r]; }
    l_run += lsum + __shfl_xor(lsum, 32);
    // pack P^T into B-frags: regs r -> j=(r&3)+8*(r>>2)+4*hi
    unsigned int w[8];
    #pragma unroll
    for (int r = 0; r < 8; ++r){
      unsigned int pk;
      asm("v_cvt_pk_bf16_f32 %0, %1, %2" : "=v"(pk) : "v"(p[2*r]), "v"(p[2*r+1]));
      w[r] = pk;
    }
    asm("v_permlane32_swap_b32 %0, %1" : "+v"(w[0]), "+v"(w[2]));
    asm("v_permlane32_swap_b32 %0, %1" : "+v"(w[1]), "+v"(w[3]));
    asm("v_permlane32_swap_b32 %0, %1" : "+v"(w[4]), "+v"(w[6]));
    asm("v_permlane32_swap_b32 %0, %1" : "+v"(w[5]), "+v"(w[7]));
    u32x4 pb0v = {w[0], w[1], w[2], w[3]};
    u32x4 pb1v = {w[4], w[5], w[6], w[7]};
    bf16x8 pb0 = __builtin_bit_cast(bf16x8, pb0v);   // k = j 0..15
    bf16x8 pb1 = __builtin_bit_cast(bf16x8, pb1v);   // k = j 16..31
    // O^T += V^T @ P^T  (m=c 32/tile, n=q 32, k=j 32)
    #pragma unroll
    for (int ct = 0; ct < 8; ++ct){
      int c = ct*32 + l31;
      int e0 = c*KVB + hi*8;
      bf16x8 va0 = __builtin_bit_cast(bf16x8, *(const u32x4*)&vl[e0 ^ ((c & 3) << 3)]);
      oa[ct] = __builtin_amdgcn_mfma_f32_32x32x16_bf16(va0, pb0, oa[ct], 0, 0, 0);
      bf16x8 va1 = __builtin_bit_cast(bf16x8, *(const u32x4*)&vl[(e0 + 16) ^ ((c & 3) << 3)]);
      oa[ct] = __builtin_amdgcn_mfma_f32_32x32x16_bf16(va1, pb1, oa[ct], 0, 0, 0);
    }
    __builtin_amdgcn_sched_barrier(0);
    __builtin_amdgcn_s_barrier();
    __builtin_amdgcn_sched_barrier(0);
  }

  // epilogue: unnormalized O (bf16) + (m,l)
  size_t orow = ((size_t)(part*4 + b) * NN + i0 + wid*32 + l31) * NC;
  #pragma unroll
  for (int ct = 0; ct < 8; ++ct){
    #pragma unroll
    for (int rq = 0; rq < 4; ++rq){
      unsigned int lo, hi2;
      asm("v_cvt_pk_bf16_f32 %0, %1, %2" : "=v"(lo)  : "v"(oa[ct][4*rq+0]), "v"(oa[ct][4*rq+1]));
      asm("v_cvt_pk_bf16_f32 %0, %1, %2" : "=v"(hi2) : "v"(oa[ct][4*rq+2]), "v"(oa[ct][4*rq+3]));
      int c = ct*32 + rq*8 + 4*hi;
      uint2 pkv; pkv.x = lo; pkv.y = hi2;
      *(uint2*)(opart + orow + c) = pkv;
    }
  }
  if (lane < 32){
    float2 mlv; mlv.x = m_run; mlv.y = l_run;
    ((float2*)ml)[(size_t)(part*4 + b) * NN + i0 + wid*32 + lane] = mlv;
  }
}

// ---------------- K4b: merge the four KV-quarters -------------------------
__global__ __launch_bounds__(256) void attn_merge(
    const unsigned short* __restrict__ opart, const float* __restrict__ ml,
    unsigned short* __restrict__ ot){
  const int t = threadIdx.x;
  const int row = blockIdx.x * 8 + (t >> 5);        // 16384 rows (b*4096+n)
  const int c0 = (t & 31) * 8;
  const float2* mlp = (const float2*)ml;
  float2 m0 = mlp[row], m1 = mlp[16384 + row], m2 = mlp[32768 + row], m3 = mlp[49152 + row];
  float M = fmaxf(fmaxf(m0.x, m1.x), fmaxf(m2.x, m3.x));
  float w0 = __expf(m0.x - M), w1 = __expf(m1.x - M);
  float w2 = __expf(m2.x - M), w3 = __expf(m3.x - M);
  float inv = 1.f / (w0*m0.y + w1*m1.y + w2*m2.y + w3*m3.y);
  w0 *= inv; w1 *= inv; w2 *= inv; w3 *= inv;
  const size_t base = (size_t)row * NC + c0;
  const size_t ps = (size_t)16384 * NC;
  u16x4 a0 = *(const u16x4*)(opart + base),        a1 = *(const u16x4*)(opart + base + 4);
  u16x4 b0 = *(const u16x4*)(opart + base + ps),   b1 = *(const u16x4*)(opart + base + ps + 4);
  u16x4 c0v = *(const u16x4*)(opart + base + 2*ps), c1 = *(const u16x4*)(opart + base + 2*ps + 4);
  u16x4 d0 = *(const u16x4*)(opart + base + 3*ps), d1 = *(const u16x4*)(opart + base + 3*ps + 4);
  u16x4 o0, o1;
  #pragma unroll
  for (int k = 0; k < 4; ++k){
    o0[k] = f2b(w0*b2f(a0[k]) + w1*b2f(b0[k]) + w2*b2f(c0v[k]) + w3*b2f(d0[k]));
    o1[k] = f2b(w0*b2f(a1[k]) + w1*b2f(b1[k]) + w2*b2f(c1[k]) + w3*b2f(d1[k]));
  }
  unsigned short* dst = ot + base;
  *(u16x4*)dst = o0; *(u16x4*)(dst + 4) = o1;
}

// ---------------- K5: out-proj + bias + residual --------------------------
__global__ __launch_bounds__(256) void out_proj(
    const unsigned short* __restrict__ ot, const float* __restrict__ W,
    const float* __restrict__ bias, const float* __restrict__ x,
    float* __restrict__ out){
  __shared__ __align__(16) unsigned short a_lds[128*32];
  __shared__ __align__(16) unsigned short b_lds[128*32];
  const int n0 = blockIdx.x * 128, oc0 = blockIdx.y * 128, b = blockIdx.z;
  const unsigned short* ob_ = ot + (size_t)b * NN * NC;
  const int t = threadIdx.x, lane = t & 63, wid = t >> 6;
  const int wm = wid >> 1, wn = wid & 1;
  const int l15 = lane & 15, lk = (lane >> 4) * 8;
  f32x4 acc[4][4] = {};
  for (int k0 = 0; k0 < NC; k0 += 32){
    __syncthreads();
    for (int ch = t; ch < 512; ch += 256){
      int row = ch >> 2, kc = (ch & 3) * 8;
      *(u32x4*)&a_lds[SWZ(row*32 + kc, row)] =
          *(const u32x4*)&ob_[(size_t)(n0 + row) * NC + k0 + kc];
    }
    for (int ch = t; ch < 512; ch += 256){
      int row = ch >> 2, kc = (ch & 3) * 8;
      const float* src = W + (size_t)(oc0 + row) * NC + k0 + kc;
      unsigned short tmp[8];
      #pragma unroll
      for (int e = 0; e < 8; ++e) tmp[e] = f2b(src[e]);
      *(u32x4*)&b_lds[SWZ(row*32 + kc, row)] = *(u32x4*)tmp;
    }
    __syncthreads();
    bf16x8 af[4], bfr[4];
    #pragma unroll
    for (int mf = 0; mf < 4; ++mf){
      int r = wm*64 + mf*16 + l15;
      af[mf] = __builtin_bit_cast(bf16x8, *(u32x4*)&a_lds[SWZ(r*32 + lk, r)]);
    }
    #pragma unroll
    for (int nf = 0; nf < 4; ++nf){
      int r = wn*64 + nf*16 + l15;
      bfr[nf] = __builtin_bit_cast(bf16x8, *(u32x4*)&b_lds[SWZ(r*32 + lk, r)]);
    }
    #pragma unroll
    for (int mf = 0; mf < 4; ++mf)
      #pragma unroll
      for (int nf = 0; nf < 4; ++nf)
        acc[mf][nf] = __builtin_amdgcn_mfma_f32_16x16x32_bf16(af[mf], bfr[nf], acc[mf][nf], 0, 0, 0);
  }
  #pragma unroll
  for (int nf = 0; nf < 4; ++nf){
    int oc = oc0 + wn*64 + nf*16 + l15;
    float bb = bias[oc];
    #pragma unroll
    for (int mf = 0; mf < 4; ++mf){
      int n = n0 + wm*64 + mf*16 + ((lane >> 4) << 2);
      size_t off = ((size_t)b * NC + oc) * NN + n;
      f32x4 xv = *(const f32x4*)&x[off];
      f32x4 r = acc[mf][nf] + xv + bb;
      *(f32x4*)&out[off] = r;
    }
  }
}

extern "C" void kernel_launch(void* const* d_in, const int* in_sizes, int n_in,
                              void* d_out, int out_size, void* d_ws, size_t ws_size,
                              hipStream_t stream){
  const float* x    = (const float*)d_in[0];
  const float* nw   = (const float*)d_in[1];
  const float* nbv  = (const float*)d_in[2];
  const float* qkvw = (const float*)d_in[3];
  const float* qkvb = (const float*)d_in[4];
  const float* outw = (const float*)d_in[5];
  const float* outb = (const float*)d_in[6];
  float* out = (float*)d_out;
  char* ws = (char*)d_ws;
  float*          part  = (float*)ws;                              // 4 KB
  unsigned short* opart = (unsigned short*)(ws + 4096);            // 32 MB
  unsigned short* hn    = (unsigned short*)(ws + 4096);            // 8 MB (dead before attn)
  unsigned short* qsep  = (unsigned short*)(ws + 4096 + 33554432); // 8 MB
  unsigned short* ksep  = qsep + (size_t)NB*NN*NC;                 // 8 MB
  unsigned short* vsep  = ksep + (size_t)NB*NN*NC;                 // 8 MB
  float*          ml    = (float*)(vsep + (size_t)NB*NN*NC);       // 512 KB
  unsigned short* ot    = qsep;   // qsep dead after attn; reuse for merged O

  gn_stats<<<256, 256, 0, stream>>>(x, part);
  gn_apply<<<4096, 256, 0, stream>>>(x, part, nw, nbv, hn);
  qkv_gemm<<<dim3(32, 6, 4), 256, 0, stream>>>(hn, qkvw, qkvb, qsep, ksep, vsep);
  attn<<<dim3(512), 256, 0, stream>>>(qsep, ksep, vsep, opart, ml);
  attn_merge<<<dim3(2048), 256, 0, stream>>>(opart, ml, ot);
  out_proj<<<dim3(32, 2, 4), 256, 0, stream>>>(ot, outw, outb, x, out);
}